// Round 2
// baseline (691.921 us; speedup 1.0000x reference)
//
#include <hip/hip_runtime.h>
#include <math.h>

#define BS 512
#define NN 256
#define RB 16
#define OMEGA_F 1.5f

// ---------------------------------------------------------------------------
// Fused SOR kernel: one block per batch, 1024 threads (16 waves).
//
// Round-6/7 diagnosis: previous 512-thread version reported VGPR_Count=128
// in ALL configs while phase-1 peak pressure was ~175 (g[8][16]=128 regs of
// G-column + acc[16] + temps) -> ~35 dwords/thread spilled to scratch.
// Evidence: WRITE_SIZE = 37 MB/dispatch vs 0.4 MB of legitimate output
// (= 141 B/thread, matching the round-5 "35 spilled regs" note that
// amdgpu_waves_per_eu(2,2) was believed to have fixed -- it did not; the
// attribute never raised the 128-reg budget, rounds 0-1 both show 128).
// Spilled g[m] fragments were reloaded from scratch inside the 60-iter
// trailing-GEMM m-loop at 2 waves/SIMD -> latency-bound at 23% occupancy.
//
// Fix: 4-way column split. 1024 threads; thread (t=tid&255, q=tid>>8 in
// {0..3}) owns j-blocks kb = 4m+q -> g[4][16] = 64 VGPRs. Peak ~110 fits
// the 128-reg budget of a 16-wave block with zero spill, and one block/CU
// = 4 waves/SIMD (2x latency hiding).
//
// Phase 1 (solve): column t of G = (D+wL)^{-1}(-(wU+(w-1)D)); solved
//   X[j][t] live in g[4][16], COMPILE-TIME indices only (round-4 lesson).
//   Trailing GEMM reads A wave-uniform from GLOBAL (scalar/L1 path,
//   round-2 lesson), X from registers. 3 partial-sum halves combine via
//   acc2[3][16][256] (48 KB); xbuf aliases acc2[0] (solver thread reads
//   acc2[0][rr][t] into s_ before writing xbuf[rr][t], same thread, same
//   address -> program order; cross-thread uses are barrier-separated).
// Transpose: 4 LDS rounds; round R writes g[R] from all 4 q-groups ->
//   rows lr=16q+rr (64 rows x 256 cols, full 64 KB), rotate-by-4 swizzle:
//   writes 2-way bank aliased (free per m136), reads aligned b128
//   (verified 0 bank conflicts in prior rounds). Reader (w=tid>>6,
//   u=tid&63) takes row 64R+u, cols [16w,16w+16) -> gi[4][4] float4.
//   Flat liveness: g frees 16 regs/round, gi fills 16/round.
// Phase 2 (iterate): e <- G e with G register-resident (gi[4][4]);
//   zero global traffic per iteration; per-batch early exit (deviation
//   from reference's global-done semantics << threshold, validated
//   rounds 1-5 of prior session).
// ---------------------------------------------------------------------------
__global__ __launch_bounds__(1024)
void sor_fused(
    const float* __restrict__ A,
    const float* __restrict__ xs,
    const float* __restrict__ x0,
    const float* __restrict__ rtol,
    const int* __restrict__ maxiter_p,
    float* __restrict__ out)
{
    const int b   = blockIdx.x;
    const int tid = threadIdx.x;
    const int t   = tid & 255;                           // column of G (phase 1)
    const int q   = tid >> 8;                            // 0..3 j-quarter (phase 1)
    const int qU  = __builtin_amdgcn_readfirstlane(q);
    const int w   = __builtin_amdgcn_readfirstlane(tid >> 6);  // wave id 0..15
    const int u   = tid & 63;                            // lane id
    const float* __restrict__ Ab = A + (size_t)b * NN * NN;

    __shared__ __align__(16) char smem[65536];
    float (*ldsA)[NN]     = (float (*)[NN])(smem);             // 16 KB A panel
    float (*acc2)[RB][NN] = (float (*)[RB][NN])(smem + 16384); // 48 KB partials (q=1..3)
    float (*xbuf)[NN]     = (float (*)[NN])(smem + 16384);     // aliases acc2[0]
    float (*ldsX)[NN]     = (float (*)[NN])(smem);             // 64 KB transpose buf
    float* rs             = (float*)(smem + 16384);            // prologue scratch
    float* e              = (float*)(smem);                    // phase-2 e[256], 1 KB
    float (*pbuf)[4][64]  = (float (*)[4][64])(smem + 1024);   // phase-2 partials 16 KB
    float* nrm            = (float*)(smem + 1024 + 16384);     // 4 norms

    const int mi = *maxiter_p;
    float* __restrict__ outb = out + (size_t)b * (mi + 1);

    // ---- prologue: e0 (register-carried), err0 = ||xs-x0||, xtol = ||xs||*rtol
    float ev = 0.f;
    if (q == 0) {                                        // tid < 256
        const float xsv = xs[b * NN + t];
        ev = xsv - x0[b * NN + t];
        float s1 = ev * ev, s2 = xsv * xsv;
        #pragma unroll
        for (int off = 32; off > 0; off >>= 1) {
            s1 += __shfl_down(s1, off);
            s2 += __shfl_down(s2, off);
        }
        if ((t & 63) == 0) { rs[t >> 6] = s1; rs[4 + (t >> 6)] = s2; }
    }
    __syncthreads();
    const float err0 = sqrtf(rs[0] + rs[1] + rs[2] + rs[3]);
    const float xtol = sqrtf(rs[4] + rs[5] + rs[6] + rs[7]) * rtol[b];
    if (tid == 0) outb[0] = err0;

    // ---- phase 1: blocked forward substitution, X in registers ----
    float g[4][RB];                                      // 64 VGPRs (SROA-promoted)
    for (int KB = 0; KB < NN / RB; ++KB) {
        const int r0 = KB * RB;
        __syncthreads();                                 // prev ldsA/xbuf/rs readers done
        // stage A panel rows [r0,r0+16): 1024 float4s, 1 per thread, coalesced
        {
            const int rr = tid >> 6, c4 = (tid & 63) << 2;
            *(float4*)&ldsA[rr][c4] = *(const float4*)&Ab[(size_t)(r0 + rr) * NN + c4];
        }
        __syncthreads();

        // trailing GEMM: acc[rr] = sum over owned j<r0 of A[r0+rr][j]*X[j][t]
        float acc[RB];
        #pragma unroll
        for (int rr = 0; rr < RB; ++rr) acc[rr] = 0.f;
        #pragma unroll
        for (int m = 0; m < 4; ++m) {
            const int kb = 4 * m + qU;
            if (kb < KB) {                               // wave-uniform branch
                const int j0 = kb * RB;
                #pragma unroll
                for (int jw = 0; jw < 4; ++jw) {
                    const float g0 = g[m][4 * jw + 0];
                    const float g1 = g[m][4 * jw + 1];
                    const float g2 = g[m][4 * jw + 2];
                    const float g3 = g[m][4 * jw + 3];
                    #pragma unroll
                    for (int hc = 0; hc < 4; ++hc) {
                        float4 a_[4];
                        #pragma unroll
                        for (int h = 0; h < 4; ++h)
                            a_[h] = *(const float4*)&Ab[(size_t)(r0 + 4 * hc + h) * NN + j0 + 4 * jw];
                        #pragma unroll
                        for (int h = 0; h < 4; ++h)
                            acc[4 * hc + h] += a_[h].x * g0 + a_[h].y * g1
                                             + a_[h].z * g2 + a_[h].w * g3;
                    }
                }
            }
        }
        // three partial quarters -> LDS
        if (q >= 1) {
            #pragma unroll
            for (int rr = 0; rr < RB; ++rr) acc2[q - 1][rr][t] = acc[rr];
        }
        __syncthreads();
        // serial 16-row solve on the q==0 waves
        if (q == 0) {
            float s_[RB];
            #pragma unroll
            for (int rr = 0; rr < RB; ++rr)
                s_[rr] = acc[rr] + acc2[0][rr][t] + acc2[1][rr][t] + acc2[2][rr][t];
            #pragma unroll
            for (int rr = 0; rr < RB; ++rr) {
                const int r = r0 + rr;
                const float a_rt = ldsA[rr][t];
                const float brt  = (t > r) ? (-OMEGA_F) * a_rt
                                 : ((t == r) ? (1.0f - OMEGA_F) * a_rt : 0.0f);
                const float diag = ldsA[rr][r];          // uniform broadcast
                const float val  = (brt - OMEGA_F * s_[rr]) / diag;
                xbuf[rr][t] = val;                       // aliases acc2[0][rr][t]: read-before-write, same thread
                #pragma unroll
                for (int rr2 = rr + 1; rr2 < RB; ++rr2)
                    s_[rr2] += ldsA[rr2][r] * val;
            }
        }
        __syncthreads();
        // owner q-quarter pulls the solved rows into registers.
        // COMPILE-TIME indices only (runtime condition is fine).
        #pragma unroll
        for (int m = 0; m < 4; ++m) {
            if (KB == 4 * m + q) {
                #pragma unroll
                for (int rr = 0; rr < RB; ++rr) g[m][rr] = xbuf[rr][t];
            }
        }
    }

    // ---- transpose: solve layout -> iterate layout, 4 rounds of 64 rows ----
    // Round R: writer (t,q) stores g[R][rr] (j = (4R+q)*16+rr = 64R+lr) at
    // ldsX[lr][(t+4*lr)&255], lr = q*16+rr. Frees 16 g-regs/round.
    // Reader (w,u) takes row 64R+u, cols [16w,16w+16): 4 aligned b128 reads.
    float4 gi[4][4];                                     // 64 VGPRs
    #pragma unroll
    for (int R = 0; R < 4; ++R) {
        __syncthreads();                                 // prior smem readers done
        #pragma unroll
        for (int rr = 0; rr < RB; ++rr) {
            const int lr = q * RB + rr;
            ldsX[lr][(t + 4 * lr) & 255] = g[R][rr];
        }
        __syncthreads();
        #pragma unroll
        for (int jj4 = 0; jj4 < 4; ++jj4) {
            const int c = 16 * w + 4 * jj4;
            gi[R][jj4] = *(const float4*)&ldsX[u][(c + 4 * u) & 255];
        }
    }
    __syncthreads();                                     // transpose reads done

    // ---- phase 2: e <- G e, err history ----
    if (tid < NN) e[tid] = ev;
    __syncthreads();

    const float4* __restrict__ e4 = (const float4*)e;
    float err = err0;
    int s = 1;
    for (; s <= mi; ++s) {
        if (!(err > xtol)) break;                        // block-uniform
        float a0 = 0.f, a1 = 0.f, a2 = 0.f, a3 = 0.f;
        #pragma unroll
        for (int jj4 = 0; jj4 < 4; ++jj4) {
            const float4 ev4 = e4[4 * w + jj4];          // wave-uniform b128 broadcast
            a0 += gi[0][jj4].x*ev4.x + gi[0][jj4].y*ev4.y + gi[0][jj4].z*ev4.z + gi[0][jj4].w*ev4.w;
            a1 += gi[1][jj4].x*ev4.x + gi[1][jj4].y*ev4.y + gi[1][jj4].z*ev4.z + gi[1][jj4].w*ev4.w;
            a2 += gi[2][jj4].x*ev4.x + gi[2][jj4].y*ev4.y + gi[2][jj4].z*ev4.z + gi[2][jj4].w*ev4.w;
            a3 += gi[3][jj4].x*ev4.x + gi[3][jj4].y*ev4.y + gi[3][jj4].z*ev4.z + gi[3][jj4].w*ev4.w;
        }
        pbuf[w][0][u] = a0;                              // lanes -> consecutive banks
        pbuf[w][1][u] = a1;
        pbuf[w][2][u] = a2;
        pbuf[w][3][u] = a3;
        __syncthreads();
        if (tid < NN) {                                  // row r = tid
            const int kk = tid >> 6, uu = tid & 63;
            float sum = 0.f;
            #pragma unroll
            for (int w2 = 0; w2 < 16; ++w2) sum += pbuf[w2][kk][uu];
            e[tid] = sum;                                // e <- G e
            float loc = sum * sum;
            #pragma unroll
            for (int off = 32; off > 0; off >>= 1) loc += __shfl_down(loc, off);
            if (uu == 0) nrm[kk] = loc;
        }
        __syncthreads();
        err = sqrtf(nrm[0] + nrm[1] + nrm[2] + nrm[3]);
        if (tid == 0) outb[s] = err;
    }
    // zero-fill the unwritten tail
    for (int idx = s + tid; idx <= mi; idx += 1024) outb[idx] = 0.f;
}

extern "C" void kernel_launch(void* const* d_in, const int* in_sizes, int n_in,
                              void* d_out, int out_size, void* d_ws, size_t ws_size,
                              hipStream_t stream) {
    const float* A     = (const float*)d_in[0];
    // d_in[1] = b: unused (error iteration e_{k+1} = G e_k needs no affine term)
    const float* xs    = (const float*)d_in[2];
    const float* theta = (const float*)d_in[3];
    const float* rtol  = (const float*)d_in[4];
    const int*   mi    = (const int*)d_in[5];
    float* out = (float*)d_out;

    // fully fused: no workspace, no memset (out[b][0] + history + tail all
    // written by the kernel every call)
    sor_fused<<<dim3(BS), dim3(1024), 0, stream>>>(
        A, xs, theta, rtol, mi, out);
}

// Round 3
// 688.656 us; speedup vs baseline: 1.0047x; 1.0047x over previous
//
#include <hip/hip_runtime.h>
#include <math.h>

#define BS 512
#define NN 256
#define RB 16
#define OMEGA_F 1.5f

// ---------------------------------------------------------------------------
// Fused SOR kernel: one block per batch, 1024 threads (16 waves).
//
// Round-8 diagnosis: register-budget control is the whole game.
//   - 512 thr, launch_bounds(512) [+ ineffective amdgpu_waves_per_eu attr]:
//     budget 128, demand ~175 -> ~35 spills, WRITE_SIZE 37 MB.
//   - 1024 thr, launch_bounds(1024): backend budgeted for 8 waves/EU ->
//     64-reg cap, demand ~115 -> ~46 spills, WRITE_SIZE 197 MB, FETCH 287 MB
//     (scratch traffic), while runtime residency was still 1 block/CU.
// The amdgpu_waves_per_eu attribute never moved VGPR_Count in any round.
// The authoritative knob is __launch_bounds__'s SECOND argument (min waves
// per EU on AMD): (1024, 4) -> amdgpu-waves-per-eu min=4 -> VGPR cap
// 2048/4/4... = 128 regs. Demand ~115 fits -> zero spill; one 16-wave
// block/CU = 4 waves/SIMD residency, matching the declared minimum
// (LDS 64 KB also limits to 1 block/CU).
//
// Phase 1 (solve): thread (t=tid&255, q=tid>>8 in {0..3}) owns j-blocks
//   kb = 4m+q; column t of G = (D+wL)^{-1}(-(wU+(w-1)D)); solved X[j][t]
//   live in g[4][16] = 64 VGPRs, COMPILE-TIME indices only (one dynamic
//   index un-SROAs the whole array). Trailing GEMM reads A wave-uniform
//   from GLOBAL (scalar/L1 path, keeps LDS pipe free), X from registers.
//   3 partial quarters combine via acc2[3][16][256] (48 KB); xbuf aliases
//   acc2[0] (solver thread reads acc2[0][rr][t] before writing xbuf[rr][t],
//   same thread -> program order; cross-thread uses barrier-separated).
// Transpose: 4 LDS rounds; round R writes g[R] from all 4 q-groups ->
//   rows lr=16q+rr (64 rows x 256 cols, full 64 KB), rotate-by-4 swizzle:
//   writes 2-way bank aliased (free per m136), reads aligned b128
//   (verified 0 bank conflicts). Reader (w=tid>>6, u=tid&63) takes row
//   64R+u, cols [16w,16w+16) -> gi[4][4] float4. Flat liveness: g frees
//   16 regs/round, gi fills 16/round.
// Phase 2 (iterate): e <- G e with G register-resident (gi[4][4]);
//   zero global traffic per iteration; per-batch early exit (deviation
//   from reference's global-done semantics << threshold, validated
//   in prior session rounds 1-5).
// ---------------------------------------------------------------------------
__global__ __launch_bounds__(1024, 4)
void sor_fused(
    const float* __restrict__ A,
    const float* __restrict__ xs,
    const float* __restrict__ x0,
    const float* __restrict__ rtol,
    const int* __restrict__ maxiter_p,
    float* __restrict__ out)
{
    const int b   = blockIdx.x;
    const int tid = threadIdx.x;
    const int t   = tid & 255;                           // column of G (phase 1)
    const int q   = tid >> 8;                            // 0..3 j-quarter (phase 1)
    const int qU  = __builtin_amdgcn_readfirstlane(q);
    const int w   = __builtin_amdgcn_readfirstlane(tid >> 6);  // wave id 0..15
    const int u   = tid & 63;                            // lane id
    const float* __restrict__ Ab = A + (size_t)b * NN * NN;

    __shared__ __align__(16) char smem[65536];
    float (*ldsA)[NN]     = (float (*)[NN])(smem);             // 16 KB A panel
    float (*acc2)[RB][NN] = (float (*)[RB][NN])(smem + 16384); // 48 KB partials (q=1..3)
    float (*xbuf)[NN]     = (float (*)[NN])(smem + 16384);     // aliases acc2[0]
    float (*ldsX)[NN]     = (float (*)[NN])(smem);             // 64 KB transpose buf
    float* rs             = (float*)(smem + 16384);            // prologue scratch
    float* e              = (float*)(smem);                    // phase-2 e[256], 1 KB
    float (*pbuf)[4][64]  = (float (*)[4][64])(smem + 1024);   // phase-2 partials 16 KB
    float* nrm            = (float*)(smem + 1024 + 16384);     // 4 norms

    const int mi = *maxiter_p;
    float* __restrict__ outb = out + (size_t)b * (mi + 1);

    // ---- prologue: e0 (register-carried), err0 = ||xs-x0||, xtol = ||xs||*rtol
    float ev = 0.f;
    if (q == 0) {                                        // tid < 256
        const float xsv = xs[b * NN + t];
        ev = xsv - x0[b * NN + t];
        float s1 = ev * ev, s2 = xsv * xsv;
        #pragma unroll
        for (int off = 32; off > 0; off >>= 1) {
            s1 += __shfl_down(s1, off);
            s2 += __shfl_down(s2, off);
        }
        if ((t & 63) == 0) { rs[t >> 6] = s1; rs[4 + (t >> 6)] = s2; }
    }
    __syncthreads();
    const float err0 = sqrtf(rs[0] + rs[1] + rs[2] + rs[3]);
    const float xtol = sqrtf(rs[4] + rs[5] + rs[6] + rs[7]) * rtol[b];
    if (tid == 0) outb[0] = err0;

    // ---- phase 1: blocked forward substitution, X in registers ----
    float g[4][RB];                                      // 64 VGPRs (SROA-promoted)
    for (int KB = 0; KB < NN / RB; ++KB) {
        const int r0 = KB * RB;
        __syncthreads();                                 // prev ldsA/xbuf/rs readers done
        // stage A panel rows [r0,r0+16): 1024 float4s, 1 per thread, coalesced
        {
            const int rr = tid >> 6, c4 = (tid & 63) << 2;
            *(float4*)&ldsA[rr][c4] = *(const float4*)&Ab[(size_t)(r0 + rr) * NN + c4];
        }
        __syncthreads();

        // trailing GEMM: acc[rr] = sum over owned j<r0 of A[r0+rr][j]*X[j][t]
        float acc[RB];
        #pragma unroll
        for (int rr = 0; rr < RB; ++rr) acc[rr] = 0.f;
        #pragma unroll
        for (int m = 0; m < 4; ++m) {
            const int kb = 4 * m + qU;
            if (kb < KB) {                               // wave-uniform branch
                const int j0 = kb * RB;
                #pragma unroll
                for (int jw = 0; jw < 4; ++jw) {
                    const float g0 = g[m][4 * jw + 0];
                    const float g1 = g[m][4 * jw + 1];
                    const float g2 = g[m][4 * jw + 2];
                    const float g3 = g[m][4 * jw + 3];
                    #pragma unroll
                    for (int hc = 0; hc < 4; ++hc) {
                        float4 a_[4];
                        #pragma unroll
                        for (int h = 0; h < 4; ++h)
                            a_[h] = *(const float4*)&Ab[(size_t)(r0 + 4 * hc + h) * NN + j0 + 4 * jw];
                        #pragma unroll
                        for (int h = 0; h < 4; ++h)
                            acc[4 * hc + h] += a_[h].x * g0 + a_[h].y * g1
                                             + a_[h].z * g2 + a_[h].w * g3;
                    }
                }
            }
        }
        // three partial quarters -> LDS
        if (q >= 1) {
            #pragma unroll
            for (int rr = 0; rr < RB; ++rr) acc2[q - 1][rr][t] = acc[rr];
        }
        __syncthreads();
        // serial 16-row solve on the q==0 waves
        if (q == 0) {
            float s_[RB];
            #pragma unroll
            for (int rr = 0; rr < RB; ++rr)
                s_[rr] = acc[rr] + acc2[0][rr][t] + acc2[1][rr][t] + acc2[2][rr][t];
            #pragma unroll
            for (int rr = 0; rr < RB; ++rr) {
                const int r = r0 + rr;
                const float a_rt = ldsA[rr][t];
                const float brt  = (t > r) ? (-OMEGA_F) * a_rt
                                 : ((t == r) ? (1.0f - OMEGA_F) * a_rt : 0.0f);
                const float diag = ldsA[rr][r];          // uniform broadcast
                const float val  = (brt - OMEGA_F * s_[rr]) / diag;
                xbuf[rr][t] = val;                       // aliases acc2[0][rr][t]: read-before-write, same thread
                #pragma unroll
                for (int rr2 = rr + 1; rr2 < RB; ++rr2)
                    s_[rr2] += ldsA[rr2][r] * val;
            }
        }
        __syncthreads();
        // owner q-quarter pulls the solved rows into registers.
        // COMPILE-TIME indices only (runtime condition is fine).
        #pragma unroll
        for (int m = 0; m < 4; ++m) {
            if (KB == 4 * m + q) {
                #pragma unroll
                for (int rr = 0; rr < RB; ++rr) g[m][rr] = xbuf[rr][t];
            }
        }
    }

    // ---- transpose: solve layout -> iterate layout, 4 rounds of 64 rows ----
    // Round R: writer (t,q) stores g[R][rr] (j = (4R+q)*16+rr = 64R+lr) at
    // ldsX[lr][(t+4*lr)&255], lr = q*16+rr. Frees 16 g-regs/round.
    // Reader (w,u) takes row 64R+u, cols [16w,16w+16): 4 aligned b128 reads.
    float4 gi[4][4];                                     // 64 VGPRs
    #pragma unroll
    for (int R = 0; R < 4; ++R) {
        __syncthreads();                                 // prior smem readers done
        #pragma unroll
        for (int rr = 0; rr < RB; ++rr) {
            const int lr = q * RB + rr;
            ldsX[lr][(t + 4 * lr) & 255] = g[R][rr];
        }
        __syncthreads();
        #pragma unroll
        for (int jj4 = 0; jj4 < 4; ++jj4) {
            const int c = 16 * w + 4 * jj4;
            gi[R][jj4] = *(const float4*)&ldsX[u][(c + 4 * u) & 255];
        }
    }
    __syncthreads();                                     // transpose reads done

    // ---- phase 2: e <- G e, err history ----
    if (tid < NN) e[tid] = ev;
    __syncthreads();

    const float4* __restrict__ e4 = (const float4*)e;
    float err = err0;
    int s = 1;
    for (; s <= mi; ++s) {
        if (!(err > xtol)) break;                        // block-uniform
        float a0 = 0.f, a1 = 0.f, a2 = 0.f, a3 = 0.f;
        #pragma unroll
        for (int jj4 = 0; jj4 < 4; ++jj4) {
            const float4 ev4 = e4[4 * w + jj4];          // wave-uniform b128 broadcast
            a0 += gi[0][jj4].x*ev4.x + gi[0][jj4].y*ev4.y + gi[0][jj4].z*ev4.z + gi[0][jj4].w*ev4.w;
            a1 += gi[1][jj4].x*ev4.x + gi[1][jj4].y*ev4.y + gi[1][jj4].z*ev4.z + gi[1][jj4].w*ev4.w;
            a2 += gi[2][jj4].x*ev4.x + gi[2][jj4].y*ev4.y + gi[2][jj4].z*ev4.z + gi[2][jj4].w*ev4.w;
            a3 += gi[3][jj4].x*ev4.x + gi[3][jj4].y*ev4.y + gi[3][jj4].z*ev4.z + gi[3][jj4].w*ev4.w;
        }
        pbuf[w][0][u] = a0;                              // lanes -> consecutive banks
        pbuf[w][1][u] = a1;
        pbuf[w][2][u] = a2;
        pbuf[w][3][u] = a3;
        __syncthreads();
        if (tid < NN) {                                  // row r = tid
            const int kk = tid >> 6, uu = tid & 63;
            float sum = 0.f;
            #pragma unroll
            for (int w2 = 0; w2 < 16; ++w2) sum += pbuf[w2][kk][uu];
            e[tid] = sum;                                // e <- G e
            float loc = sum * sum;
            #pragma unroll
            for (int off = 32; off > 0; off >>= 1) loc += __shfl_down(loc, off);
            if (uu == 0) nrm[kk] = loc;
        }
        __syncthreads();
        err = sqrtf(nrm[0] + nrm[1] + nrm[2] + nrm[3]);
        if (tid == 0) outb[s] = err;
    }
    // zero-fill the unwritten tail
    for (int idx = s + tid; idx <= mi; idx += 1024) outb[idx] = 0.f;
}

extern "C" void kernel_launch(void* const* d_in, const int* in_sizes, int n_in,
                              void* d_out, int out_size, void* d_ws, size_t ws_size,
                              hipStream_t stream) {
    const float* A     = (const float*)d_in[0];
    // d_in[1] = b: unused (error iteration e_{k+1} = G e_k needs no affine term)
    const float* xs    = (const float*)d_in[2];
    const float* theta = (const float*)d_in[3];
    const float* rtol  = (const float*)d_in[4];
    const int*   mi    = (const int*)d_in[5];
    float* out = (float*)d_out;

    // fully fused: no workspace, no memset (out[b][0] + history + tail all
    // written by the kernel every call)
    sor_fused<<<dim3(BS), dim3(1024), 0, stream>>>(
        A, xs, theta, rtol, mi, out);
}